// Round 1
// baseline (576.023 us; speedup 1.0000x reference)
//
#include <hip/hip_runtime.h>

#define SS 2048
#define DD 1024
#define HH 16
#define DHD 64
#define HSN (HH * SS)  // 32768

typedef __bf16 bf16x8 __attribute__((ext_vector_type(8)));
typedef __bf16 bf16x4 __attribute__((ext_vector_type(4)));
typedef float f32x4 __attribute__((ext_vector_type(4)));

// ---------------- fp32 -> bf16 convert ----------------
__global__ __launch_bounds__(256) void cvt_bf16_kernel(const float* __restrict__ in,
                                                       __bf16* __restrict__ out, int n4) {
  int i = blockIdx.x * 256 + threadIdx.x;
  if (i >= n4) return;
  const float4 v = ((const float4*)in)[i];
  bf16x4 r;
  r[0] = (__bf16)v.x; r[1] = (__bf16)v.y; r[2] = (__bf16)v.z; r[3] = (__bf16)v.w;
  *(bf16x4*)&out[(long)i * 4] = r;
}

// ---------------- NT GEMM: C[M,N] = A[M,K] * B[N,K]^T ----------------
// MODE 0: bf16 out, MODE 1: bf16 out * 0.125 (Q scale), MODE 2: fp32 out
template <int MODE>
__global__ __launch_bounds__(256) void gemm_nt(const __bf16* __restrict__ A,
                                               const __bf16* __restrict__ B,
                                               void* __restrict__ Cout,
                                               int M, int N, int K) {
  __shared__ __bf16 As[64][40];  // 32 k + pad to 40 (80B rows, 2-way banks = free)
  __shared__ __bf16 Bs[64][40];
  const int tid = threadIdx.x;
  const int lane = tid & 63;
  const int wave = tid >> 6;           // 0..3
  const int wm = (wave >> 1) * 32;
  const int wn = (wave & 1) * 32;
  const long m0 = (long)blockIdx.y * 64;
  const long n0 = (long)blockIdx.x * 64;
  const int g = lane >> 4;             // 0..3
  const int r16 = lane & 15;
  const int lrow = tid >> 2;           // 0..63
  const int lseg = (tid & 3) * 8;      // 0,8,16,24

  f32x4 acc[2][2] = {};

  for (int k0 = 0; k0 < K; k0 += 32) {
    *(bf16x8*)&As[lrow][lseg] = *(const bf16x8*)&A[(m0 + lrow) * K + k0 + lseg];
    *(bf16x8*)&Bs[lrow][lseg] = *(const bf16x8*)&B[(n0 + lrow) * K + k0 + lseg];
    __syncthreads();
    bf16x8 af[2], bfr[2];
#pragma unroll
    for (int r = 0; r < 2; ++r) af[r] = *(const bf16x8*)&As[wm + r * 16 + r16][g * 8];
#pragma unroll
    for (int c = 0; c < 2; ++c) bfr[c] = *(const bf16x8*)&Bs[wn + c * 16 + r16][g * 8];
#pragma unroll
    for (int r = 0; r < 2; ++r)
#pragma unroll
      for (int c = 0; c < 2; ++c)
        acc[r][c] = __builtin_amdgcn_mfma_f32_16x16x32_bf16(af[r], bfr[c], acc[r][c], 0, 0, 0);
    __syncthreads();
  }

#pragma unroll
  for (int r = 0; r < 2; ++r)
#pragma unroll
    for (int c = 0; c < 2; ++c)
#pragma unroll
      for (int i = 0; i < 4; ++i) {
        const long row = m0 + wm + r * 16 + g * 4 + i;  // C/D: row=(lane>>4)*4+reg
        const long col = n0 + wn + c * 16 + r16;        // C/D: col=lane&15
        float v = acc[r][c][i];
        if (MODE == 1) v *= 0.125f;
        if (MODE == 2) ((float*)Cout)[row * N + col] = v;
        else           ((__bf16*)Cout)[row * N + col] = (__bf16)v;
      }
}

// ---------------- bf16 transpose: out[c][r] = in[r][c] ----------------
__global__ __launch_bounds__(256) void transpose_bf16(const __bf16* __restrict__ in,
                                                      __bf16* __restrict__ out,
                                                      int R, int C) {
  __shared__ __bf16 t[64][72];
  const int tid = threadIdx.x;
  const long r0 = (long)blockIdx.y * 64;
  const long c0 = (long)blockIdx.x * 64;
  const int row = tid >> 2;
#pragma unroll
  for (int it = 0; it < 2; ++it) {
    const int seg = (tid & 3) * 8 + it * 32;
    *(bf16x8*)&t[row][seg] = *(const bf16x8*)&in[(r0 + row) * C + c0 + seg];
  }
  __syncthreads();
#pragma unroll
  for (int it = 0; it < 2; ++it) {
    const int seg = (tid & 3) * 8 + it * 32;
    bf16x8 v;
#pragma unroll
    for (int j = 0; j < 8; ++j) v[j] = t[seg + j][row];
    *(bf16x8*)&out[(c0 + row) * R + r0 + seg] = v;
  }
}

// ---------------- flash attention: one block = (64 q rows, 1 head) ----------------
// Q pre-scaled by 1/sqrt(DH). Vt is [D, S] (transposed V).
__global__ __launch_bounds__(256) void attn_kernel(
    const __bf16* __restrict__ Q, const __bf16* __restrict__ K,
    const __bf16* __restrict__ Vt, const float* __restrict__ bias,
    const int* __restrict__ mask, __bf16* __restrict__ Aout) {
  __shared__ __bf16 Ks[32][72];       // 32 kv rows x 64 dh (pad 72: 144B rows)
  __shared__ __bf16 Vts[64][40];      // 64 d rows x 32 kv (pad 40: 80B rows)
  __shared__ __bf16 Ps[4][16][40];    // per-wave P: 16 q x 32 kv (pad 40)
  const int tid = threadIdx.x;
  const int lane = tid & 63;
  const int wave = tid >> 6;
  const int h = blockIdx.y;
  const int q0 = blockIdx.x * 64 + wave * 16;
  const int g = lane >> 4;
  const int r16 = lane & 15;

  // Q A-fragments (held for whole kernel): A[m=lane&15][k=(lane>>4)*8+j]
  bf16x8 qf[2];
#pragma unroll
  for (int m = 0; m < 2; ++m)
    qf[m] = *(const bf16x8*)&Q[(long)(q0 + r16) * DD + h * DHD + m * 32 + g * 8];

  f32x4 o[4] = {};
  float mrow[4], lsum[4];
#pragma unroll
  for (int i = 0; i < 4; ++i) { mrow[i] = -__builtin_inff(); lsum[i] = 0.f; }

  const int krow = tid >> 3, kseg = (tid & 7) * 8;
  const int vrow = tid >> 2, vseg = (tid & 3) * 8;

  for (int kv0 = 0; kv0 < SS; kv0 += 32) {
    *(bf16x8*)&Ks[krow][kseg]  = *(const bf16x8*)&K[(long)(kv0 + krow) * DD + h * DHD + kseg];
    *(bf16x8*)&Vts[vrow][vseg] = *(const bf16x8*)&Vt[(long)(h * DHD + vrow) * SS + kv0 + vseg];
    __syncthreads();

#pragma unroll
    for (int t = 0; t < 2; ++t) {
      // B-frag: B[k=(lane>>4)*8+j][n=lane&15] = K[kv=n][dh=k]
      bf16x8 kf0 = *(const bf16x8*)&Ks[t * 16 + r16][g * 8];
      bf16x8 kf1 = *(const bf16x8*)&Ks[t * 16 + r16][32 + g * 8];
      f32x4 s = {};
      s = __builtin_amdgcn_mfma_f32_16x16x32_bf16(qf[0], kf0, s, 0, 0, 0);
      s = __builtin_amdgcn_mfma_f32_16x16x32_bf16(qf[1], kf1, s, 0, 0, 0);
      const int kcol = kv0 + t * 16 + r16;
#pragma unroll
      for (int i = 0; i < 4; ++i) {
        const int qrow = q0 + g * 4 + i;
        float sv = s[i] + bias[(long)qrow * HSN + h * SS + kcol];
        if (mask[(long)qrow * SS + kcol] == 0) sv = -3.4028235e38f;  // finfo(f32).min
        float tmax = sv;
        tmax = fmaxf(tmax, __shfl_xor(tmax, 1));
        tmax = fmaxf(tmax, __shfl_xor(tmax, 2));
        tmax = fmaxf(tmax, __shfl_xor(tmax, 4));
        tmax = fmaxf(tmax, __shfl_xor(tmax, 8));
        const float mnew = fmaxf(mrow[i], tmax);
        const float alpha = __expf(mrow[i] - mnew);  // exp(-inf)=0 on first tile
        const float p = __expf(sv - mnew);
        float psum = p;
        psum += __shfl_xor(psum, 1);
        psum += __shfl_xor(psum, 2);
        psum += __shfl_xor(psum, 4);
        psum += __shfl_xor(psum, 8);
        lsum[i] = lsum[i] * alpha + psum;
        mrow[i] = mnew;
#pragma unroll
        for (int db = 0; db < 4; ++db) o[db][i] *= alpha;
        // C-layout -> LDS (row = g*4+i, col = t*16 + r16)
        Ps[wave][g * 4 + i][t * 16 + r16] = (__bf16)p;
      }
    }

    // P back as A-frag (LDS round-trip transform), V B-frags from Vt tile
    bf16x8 pf = *(const bf16x8*)&Ps[wave][r16][g * 8];
#pragma unroll
    for (int db = 0; db < 4; ++db) {
      bf16x8 vf = *(const bf16x8*)&Vts[db * 16 + r16][g * 8];
      o[db] = __builtin_amdgcn_mfma_f32_16x16x32_bf16(pf, vf, o[db], 0, 0, 0);
    }
    __syncthreads();
  }

#pragma unroll
  for (int db = 0; db < 4; ++db)
#pragma unroll
    for (int i = 0; i < 4; ++i) {
      const int row = q0 + g * 4 + i;
      Aout[(long)row * DD + h * DHD + db * 16 + r16] = (__bf16)(o[db][i] / lsum[i]);
    }
}

// ---------------- residual + LayerNorm ----------------
__global__ __launch_bounds__(256) void ln_kernel(const float* __restrict__ attn_out,
                                                 const float* __restrict__ x,
                                                 const float* __restrict__ w,
                                                 const float* __restrict__ b,
                                                 float* __restrict__ out) {
  const long row = blockIdx.x;
  const int tid = threadIdx.x;
  float v[4];
  float s = 0.f, s2 = 0.f;
#pragma unroll
  for (int j = 0; j < 4; ++j) {
    const int d = tid + j * 256;
    const float r = attn_out[row * DD + d] + x[row * DD + d];
    v[j] = r; s += r; s2 += r * r;
  }
#pragma unroll
  for (int off = 1; off < 64; off <<= 1) {
    s  += __shfl_xor(s, off);
    s2 += __shfl_xor(s2, off);
  }
  __shared__ float ss[4], ss2[4];
  if ((tid & 63) == 0) { ss[tid >> 6] = s; ss2[tid >> 6] = s2; }
  __syncthreads();
  s = ss[0] + ss[1] + ss[2] + ss[3];
  s2 = ss2[0] + ss2[1] + ss2[2] + ss2[3];
  const float mean = s * (1.f / DD);
  const float var = s2 * (1.f / DD) - mean * mean;
  const float inv = rsqrtf(var + 1e-5f);
#pragma unroll
  for (int j = 0; j < 4; ++j) {
    const int d = tid + j * 256;
    out[row * DD + d] = (v[j] - mean) * inv * w[d] + b[d];
  }
}

// ---------------- host launch ----------------
extern "C" void kernel_launch(void* const* d_in, const int* in_sizes, int n_in,
                              void* d_out, int out_size, void* d_ws, size_t ws_size,
                              hipStream_t stream) {
  const float* x    = (const float*)d_in[0];
  const float* bias = (const float*)d_in[1];
  const int*   mask = (const int*)d_in[2];
  const float* Wq   = (const float*)d_in[3];
  const float* Wk   = (const float*)d_in[4];
  const float* Wv   = (const float*)d_in[5];
  const float* Wo   = (const float*)d_in[6];
  const float* lnw  = (const float*)d_in[7];
  const float* lnb  = (const float*)d_in[8];
  float* out = (float*)d_out;

  char* ws = (char*)d_ws;
  const size_t MB = 1024 * 1024;
  __bf16* xb   = (__bf16*)(ws + 0);        // 4 MB  (2048x1024)
  __bf16* Wqb  = (__bf16*)(ws + 4 * MB);   // 2 MB
  __bf16* Wkb  = (__bf16*)(ws + 6 * MB);
  __bf16* Wvb  = (__bf16*)(ws + 8 * MB);
  __bf16* Wob  = (__bf16*)(ws + 10 * MB);
  __bf16* Qb   = (__bf16*)(ws + 12 * MB);  // 4 MB each
  __bf16* Kb   = (__bf16*)(ws + 16 * MB);
  __bf16* Vb   = (__bf16*)(ws + 20 * MB);
  __bf16* Vtb  = (__bf16*)(ws + 24 * MB);  // [1024, 2048]
  __bf16* Atnb = (__bf16*)(ws + 28 * MB);  // attn context bf16 [2048,1024]
  float*  AOut = (float*)(ws + 32 * MB);   // attn @ Wo^T fp32, 8 MB

  // converts
  cvt_bf16_kernel<<<dim3(SS * DD / 1024), dim3(256), 0, stream>>>(x, xb, SS * DD / 4);
  cvt_bf16_kernel<<<dim3(DD * DD / 1024), dim3(256), 0, stream>>>(Wq, Wqb, DD * DD / 4);
  cvt_bf16_kernel<<<dim3(DD * DD / 1024), dim3(256), 0, stream>>>(Wk, Wkb, DD * DD / 4);
  cvt_bf16_kernel<<<dim3(DD * DD / 1024), dim3(256), 0, stream>>>(Wv, Wvb, DD * DD / 4);
  cvt_bf16_kernel<<<dim3(DD * DD / 1024), dim3(256), 0, stream>>>(Wo, Wob, DD * DD / 4);

  // projections: C[s,d] = sum_k x[s,k] W[d,k]
  dim3 ggrid(DD / 64, SS / 64);
  gemm_nt<1><<<ggrid, dim3(256), 0, stream>>>(xb, Wqb, Qb, SS, DD, DD);  // Q * 0.125
  gemm_nt<0><<<ggrid, dim3(256), 0, stream>>>(xb, Wkb, Kb, SS, DD, DD);
  gemm_nt<0><<<ggrid, dim3(256), 0, stream>>>(xb, Wvb, Vb, SS, DD, DD);

  // V^T [D, S]
  transpose_bf16<<<dim3(DD / 64, SS / 64), dim3(256), 0, stream>>>(Vb, Vtb, SS, DD);

  // attention
  attn_kernel<<<dim3(SS / 64, HH), dim3(256), 0, stream>>>(Qb, Kb, Vtb, bias, mask, Atnb);

  // out projection (fp32 out)
  gemm_nt<2><<<ggrid, dim3(256), 0, stream>>>(Atnb, Wob, AOut, SS, DD, DD);

  // residual + LN
  ln_kernel<<<dim3(SS), dim3(256), 0, stream>>>(AOut, x, lnw, lnb, out);
}